// Round 14
// baseline (190.502 us; speedup 1.0000x reference)
//
#include <hip/hip_runtime.h>
#include <hip/hip_fp16.h>
#include <math.h>

// GAT 2-layer forward on MI355X.
// CSR build: fused single kernel (slab scatter -> device grid barrier ->
//            per-bucket counting sort). Per-edge atomics are LDS-only.
// Per layer:
//   mfma_gemm: grid-stride persistent blocks; W^T staged once per block;
//              h = x@W via mfma_f32_16x16x32_f16, fused alpha epilogue.
//   aggregate: wave = 2 dst nodes; 8 c-lanes own 8 channels (f16x8 16B
//              gathers) x 4 edge-offset lanes; 16 edges/node in flight;
//              weight computed in-kernel (no-max softmax).

constexpr int FDIM = 64;
constexpr int BSHIFT = 9;                 // 512 nodes per bucket
constexpr int BMASK = (1 << BSHIFT) - 1;  // 511
constexpr int EDGE_TILE = 4096;           // edges per scatter block
constexpr int SLAB_CAP = 8192;            // per-bucket slab capacity (mean 5.6k)

using f16 = _Float16;
typedef f16 f16x8 __attribute__((ext_vector_type(8)));
typedef f16 f16x4 __attribute__((ext_vector_type(4)));
typedef float f32x4 __attribute__((ext_vector_type(4)));

// ---------------- small utility ----------------

__global__ void zero_kernel(int* __restrict__ p, int n) {
  int i = blockIdx.x * blockDim.x + threadIdx.x;
  if (i < n) p[i] = 0;
}

// ---------------- fused CSR build ----------------
// Phase A (all blocks): per-tile LDS histogram -> per-bucket slab reservation
// (1 global atomic per block x bucket) -> scatter packed edges into slabs.
// Device barrier (atomic arrive + spin; all blocks co-resident: 269 blocks,
// <=6KB LDS, low VGPR on 256 CUs).
// Phase B (blocks < NB): per-bucket counting sort -> row_start + esrc.

__global__ __launch_bounds__(256) void fused_csr_kernel(
    const int* __restrict__ ei, int E, int Etot, int NB, int nTiles,
    int* __restrict__ bcnt, unsigned* __restrict__ slab,
    int N, int* __restrict__ row_start, int* __restrict__ esrc,
    int* __restrict__ sync) {
  __shared__ int hist[512];
  __shared__ int excl[512];
  __shared__ int cur[512];
  __shared__ int sbase;
  int t = threadIdx.x;

  // ---- Phase A: scatter ----
  for (int tile = blockIdx.x; tile < nTiles; tile += gridDim.x) {
    for (int b = t; b < NB; b += 256) hist[b] = 0;
    __syncthreads();
    int i0 = tile * EDGE_TILE;
    int iend = min(i0 + EDGE_TILE, Etot);
    for (int i = i0 + t; i < iend; i += 256) {
      int dst = (i < E) ? ei[E + i] : (i - E);  // self-loops appended
      atomicAdd(&hist[dst >> BSHIFT], 1);
    }
    __syncthreads();
    for (int b = t; b < NB; b += 256)
      cur[b] = hist[b] ? atomicAdd(&bcnt[b], hist[b]) : 0;
    __syncthreads();
    for (int i = i0 + t; i < iend; i += 256) {
      int src, dst;
      if (i < E) { src = ei[i]; dst = ei[E + i]; }
      else       { src = i - E; dst = i - E; }
      int b = dst >> BSHIFT;
      int pos = atomicAdd(&cur[b], 1);
      if (pos < SLAB_CAP)
        slab[(size_t)b * SLAB_CAP + pos] =
            ((unsigned)src << BSHIFT) | (unsigned)(dst & BMASK);
    }
    __syncthreads();
  }

  // ---- device grid barrier ----
  __threadfence();
  if (t == 0) atomicAdd(sync, 1);
  int b = blockIdx.x;
  if (b >= NB) return;
  if (t == 0) {
    while (atomicAdd(sync, 0) < (int)gridDim.x) { }
  }
  __syncthreads();
  __threadfence();

  // ---- Phase B: per-bucket counting sort ----
  if (t < 64) {
    int ssum = 0;
    for (int i = t; i < b; i += 64) ssum += bcnt[i];
#pragma unroll
    for (int off = 32; off > 0; off >>= 1) ssum += __shfl_xor(ssum, off, 64);
    if (t == 0) sbase = ssum;
  }
  hist[t] = 0;
  hist[256 + t] = 0;
  __syncthreads();
  int base = sbase;
  int cnt = min(bcnt[b], SLAB_CAP);
  const unsigned* sp = slab + (size_t)b * SLAB_CAP;
  for (int i = t; i < cnt; i += 256)
    atomicAdd(&hist[sp[i] & (unsigned)BMASK], 1);
  __syncthreads();
  int h0 = hist[2 * t], h1 = hist[2 * t + 1];
  int s = h0 + h1;
  int lane = t & 63, w = t >> 6;
  int x = s;
#pragma unroll
  for (int off = 1; off < 64; off <<= 1) {
    int u = __shfl_up(x, off, 64);
    if (lane >= off) x += u;
  }
  __shared__ int wsum[4];
  if (lane == 63) wsum[w] = x;
  __syncthreads();
  int add = 0;
#pragma unroll
  for (int k = 0; k < 4; ++k) add += (k < w) ? wsum[k] : 0;
  int e0 = x + add - s;
  excl[2 * t] = e0;
  excl[2 * t + 1] = e0 + h0;
  cur[2 * t] = e0;
  cur[2 * t + 1] = e0 + h0;
  __syncthreads();
  int node0 = b << BSHIFT;
#pragma unroll
  for (int k = 0; k < 2; ++k) {
    int slot = k * 256 + t;
    int node = node0 + slot;
    if (node < N) row_start[node] = base + excl[slot];
  }
  if (b == NB - 1 && t == 0) row_start[N] = Etot;
  for (int i = t; i < cnt; i += 256) {
    unsigned p = sp[i];
    int pos = base + atomicAdd(&cur[p & (unsigned)BMASK], 1);
    esrc[pos] = (int)(p >> BSHIFT);
  }
}

// ---------------- MFMA GEMM (x @ W) + attention logits ----------------
// Grid-stride persistent blocks; W^T staged into LDS ONCE per block.

template <int HEADS, typename IN>
__global__ __launch_bounds__(256) void mfma_gemm_kernel(
    const IN* __restrict__ X, const float* __restrict__ W,
    const float* __restrict__ a_s, const float* __restrict__ a_d, int N,
    __half* __restrict__ H, float* __restrict__ AS, float* __restrict__ AD,
    int nRowTiles) {
  __shared__ f16 Xs[64 * 72];
  __shared__ f16 Wt[64 * 72];
  int t = threadIdx.x;

#pragma unroll
  for (int i = 0; i < 16; ++i) {
    int idx = i * 256 + t;
    int k = idx >> 6, c = idx & 63;
    Wt[c * 72 + k] = (f16)W[idx];
  }

  int lane = t & 63, wid = t >> 6;
  int m0 = wid * 16;
  int li = lane & 15, lk = lane >> 4;
  int ko = lk * 8;
  float asc[4], adc[4];
#pragma unroll
  for (int q = 0; q < 4; ++q) {
    asc[q] = a_s[q * 16 + li];
    adc[q] = a_d[q * 16 + li];
  }

  for (int tile = blockIdx.x; tile < nRowTiles; tile += gridDim.x) {
    int row0 = tile * 64;
    __syncthreads();  // prior iteration finished reading Xs (also fences Wt)
    if constexpr (sizeof(IN) == 4) {
#pragma unroll
      for (int i = 0; i < 4; ++i) {
        int idx = (i * 256 + t) * 4;
        int r = idx >> 6, k = idx & 63;
        int rg = min(row0 + r, N - 1);
        float4 f = *reinterpret_cast<const float4*>(
            reinterpret_cast<const float*>(X) + (size_t)rg * 64 + k);
        f16x4 v = {(f16)f.x, (f16)f.y, (f16)f.z, (f16)f.w};
        *reinterpret_cast<f16x4*>(&Xs[r * 72 + k]) = v;
      }
    } else {
#pragma unroll
      for (int i = 0; i < 2; ++i) {
        int idx = (i * 256 + t) * 8;
        int r = idx >> 6, k = idx & 63;
        int rg = min(row0 + r, N - 1);
        f16x8 v = *reinterpret_cast<const f16x8*>(
            reinterpret_cast<const f16*>(X) + (size_t)rg * 64 + k);
        *reinterpret_cast<f16x8*>(&Xs[r * 72 + k]) = v;
      }
    }
    __syncthreads();

    f16x8 a_lo = *reinterpret_cast<const f16x8*>(&Xs[(m0 + li) * 72 + ko]);
    f16x8 a_hi = *reinterpret_cast<const f16x8*>(&Xs[(m0 + li) * 72 + 32 + ko]);

    f32x4 acc[4];
#pragma unroll
    for (int q = 0; q < 4; ++q) acc[q] = (f32x4){0.f, 0.f, 0.f, 0.f};
#pragma unroll
    for (int q = 0; q < 4; ++q) {
      int c0 = q * 16 + li;
      f16x8 b_lo = *reinterpret_cast<const f16x8*>(&Wt[c0 * 72 + ko]);
      f16x8 b_hi = *reinterpret_cast<const f16x8*>(&Wt[c0 * 72 + 32 + ko]);
      acc[q] = __builtin_amdgcn_mfma_f32_16x16x32_f16(a_lo, b_lo, acc[q], 0, 0, 0);
      acc[q] = __builtin_amdgcn_mfma_f32_16x16x32_f16(a_hi, b_hi, acc[q], 0, 0, 0);
    }

    int rbase = row0 + m0 + lk * 4;
#pragma unroll
    for (int r = 0; r < 4; ++r) {
      int grow = rbase + r;
      if (grow < N) {
#pragma unroll
        for (int q = 0; q < 4; ++q)
          H[(size_t)grow * 64 + q * 16 + li] = __float2half((float)acc[q][r]);
      }
    }

    if constexpr (HEADS == 4) {
      float ps[4][4], pd[4][4];
#pragma unroll
      for (int q = 0; q < 4; ++q)
#pragma unroll
        for (int r = 0; r < 4; ++r) {
          ps[q][r] = (float)acc[q][r] * asc[q];
          pd[q][r] = (float)acc[q][r] * adc[q];
        }
#pragma unroll
      for (int off = 1; off < 16; off <<= 1)
#pragma unroll
        for (int q = 0; q < 4; ++q)
#pragma unroll
          for (int r = 0; r < 4; ++r) {
            ps[q][r] += __shfl_xor(ps[q][r], off, 64);
            pd[q][r] += __shfl_xor(pd[q][r], off, 64);
          }
      if (li == 0) {
#pragma unroll
        for (int r = 0; r < 4; ++r) {
          int grow = rbase + r;
          if (grow < N) {
#pragma unroll
            for (int q = 0; q < 4; ++q) {
              AS[(size_t)grow * 4 + q] = ps[q][r];
              AD[(size_t)grow * 4 + q] = pd[q][r];
            }
          }
        }
      }
    } else {
      float ps[4], pd[4];
#pragma unroll
      for (int r = 0; r < 4; ++r) {
        ps[r] = 0.f; pd[r] = 0.f;
#pragma unroll
        for (int q = 0; q < 4; ++q) {
          ps[r] = fmaf((float)acc[q][r], asc[q], ps[r]);
          pd[r] = fmaf((float)acc[q][r], adc[q], pd[r]);
        }
      }
#pragma unroll
      for (int off = 1; off < 16; off <<= 1)
#pragma unroll
        for (int r = 0; r < 4; ++r) {
          ps[r] += __shfl_xor(ps[r], off, 64);
          pd[r] += __shfl_xor(pd[r], off, 64);
        }
      if (li == 0) {
#pragma unroll
        for (int r = 0; r < 4; ++r) {
          int grow = rbase + r;
          if (grow < N) { AS[grow] = ps[r]; AD[grow] = pd[r]; }
        }
      }
    }
  }
}

// ---------------- aggregation (f16x8 channels, 16 edges in flight) --------

template <int HEADS, bool FINAL, typename OUTT>
__global__ __launch_bounds__(256) void aggregate_kernel(
    const int* __restrict__ row_start, const int* __restrict__ esrc,
    const __half* __restrict__ H, const float* __restrict__ AS,
    const float* __restrict__ AD, const float* __restrict__ bias, int N,
    OUTT* __restrict__ OUT) {
  int t = threadIdx.x;
  int wid = t >> 6;
  int half = (t >> 5) & 1;
  int ll = t & 31;
  int c = ll & 7;            // channel octet: channels 8c..8c+7
  int eo = ll >> 3;          // edge offset lane 0..3
  int n = blockIdx.x * 8 + wid * 2 + half;

  int head = (HEADS == 4) ? (c >> 1) : 0;

  int rs = 0, re = 0;
  float ad = 0.f;
  if (n < N) {
    rs = row_start[n];
    re = row_start[n + 1];
    ad = AD[(size_t)n * HEADS + head];
  }
  int deg = re - rs;
  int degO = __shfl_xor(deg, 32, 64);
  int degmax = max(deg, degO);

  const f16* Hp = reinterpret_cast<const f16*>(H);

  float d = 0.f;
  float a[8] = {0.f, 0.f, 0.f, 0.f, 0.f, 0.f, 0.f, 0.f};

  for (int i = 0; i < degmax; i += 16) {
    int sv[4];
    float ev[4];
    f16x8 hv[4];
#pragma unroll
    for (int k = 0; k < 4; ++k) {
      int o = i + 4 * k + eo;
      int oc = max(min(o, deg - 1), 0);  // deg >= 1 always (self-loops)
      sv[k] = esrc[rs + oc];
    }
#pragma unroll
    for (int k = 0; k < 4; ++k) {
      ev[k] = AS[(unsigned)sv[k] * HEADS + (unsigned)head];
      hv[k] = *reinterpret_cast<const f16x8*>(&Hp[(size_t)sv[k] * 64 + c * 8]);
    }
#pragma unroll
    for (int k = 0; k < 4; ++k) {
      int o = i + 4 * k + eo;
      float e = ev[k] + ad;
      e = fmaxf(e, 0.2f * e);            // LeakyReLU(0.2)
      float w = (o < deg) ? __expf(e) : 0.f;
      d += w;
#pragma unroll
      for (int j = 0; j < 8; ++j) a[j] = fmaf(w, (float)hv[k][j], a[j]);
    }
  }

  // merge the 4 edge-offset lanes (xor 8,16 stay within the node's 32 lanes)
  d += __shfl_xor(d, 8, 64);
  d += __shfl_xor(d, 16, 64);
#pragma unroll
  for (int j = 0; j < 8; ++j) {
    a[j] += __shfl_xor(a[j], 8, 64);
    a[j] += __shfl_xor(a[j], 16, 64);
  }

  if (n >= N) return;

  float inv = 1.f / (d + 1e-16f);
  float4 b0 = reinterpret_cast<const float4*>(bias)[c * 2];
  float4 b1 = reinterpret_cast<const float4*>(bias)[c * 2 + 1];
  float v[8];
  v[0] = a[0] * inv + b0.x;
  v[1] = a[1] * inv + b0.y;
  v[2] = a[2] * inv + b0.z;
  v[3] = a[3] * inv + b0.w;
  v[4] = a[4] * inv + b1.x;
  v[5] = a[5] * inv + b1.y;
  v[6] = a[6] * inv + b1.z;
  v[7] = a[7] * inv + b1.w;

  if constexpr (FINAL) {
    float ss = 0.f;
#pragma unroll
    for (int j = 0; j < 8; ++j) ss += v[j] * v[j];
    ss += __shfl_xor(ss, 1, 64);
    ss += __shfl_xor(ss, 2, 64);
    ss += __shfl_xor(ss, 4, 64);
    float rn = 1.f / fmaxf(sqrtf(ss), 1e-12f);
    if (eo == 0) {
      float4* O4 = reinterpret_cast<float4*>(OUT);
      O4[(size_t)n * 16 + c * 2] =
          make_float4(v[0] * rn, v[1] * rn, v[2] * rn, v[3] * rn);
      O4[(size_t)n * 16 + c * 2 + 1] =
          make_float4(v[4] * rn, v[5] * rn, v[6] * rn, v[7] * rn);
    }
  } else {
#pragma unroll
    for (int j = 0; j < 8; ++j) v[j] = v[j] > 0.f ? v[j] : expm1f(v[j]);
    if (eo == 0) {
      f16x8 o = {(f16)v[0], (f16)v[1], (f16)v[2], (f16)v[3],
                 (f16)v[4], (f16)v[5], (f16)v[6], (f16)v[7]};
      reinterpret_cast<f16x8*>(OUT)[(size_t)n * 8 + c] = o;
    }
  }
}

// ---------------- launch ----------------

extern "C" void kernel_launch(void* const* d_in, const int* in_sizes, int n_in,
                              void* d_out, int out_size, void* d_ws,
                              size_t ws_size, hipStream_t stream) {
  const int* ei = (const int*)d_in[0];          // [2, E]
  const float* emb = (const float*)d_in[1];     // [N, 64]
  const float* W1 = (const float*)d_in[2];
  const float* as1 = (const float*)d_in[3];
  const float* ad1 = (const float*)d_in[4];
  const float* b1 = (const float*)d_in[5];
  const float* W2 = (const float*)d_in[6];
  const float* as2 = (const float*)d_in[7];
  const float* ad2 = (const float*)d_in[8];
  const float* b2 = (const float*)d_in[9];
  float* out = (float*)d_out;

  int E = in_sizes[0] / 2;
  int N = in_sizes[1] / FDIM;
  int Etot = E + N;
  int NB = (N + BMASK) >> BSHIFT;           // buckets of 512 nodes
  int nTiles = (Etot + EDGE_TILE - 1) / EDGE_TILE;

  char* ws = (char*)d_ws;
  size_t off = 0;
  auto alloc = [&](size_t bytes) -> void* {
    void* p = ws + off;
    off += (bytes + 255) & ~(size_t)255;
    return p;
  };
  int* bcnt = (int*)alloc((size_t)(NB + 1) * sizeof(int));  // +1 = sync ctr
  int* syncc = bcnt + NB;
  unsigned* slab = (unsigned*)alloc((size_t)NB * SLAB_CAP * sizeof(unsigned));
  int* row_start = (int*)alloc((size_t)(N + 1) * sizeof(int));
  int* esrc = (int*)alloc((size_t)Etot * sizeof(int));
  __half* hbuf = (__half*)alloc((size_t)N * FDIM * sizeof(__half));
  __half* xbuf = (__half*)alloc((size_t)N * FDIM * sizeof(__half));
  float* AS = (float*)alloc((size_t)N * 4 * sizeof(float));
  float* AD = (float*)alloc((size_t)N * 4 * sizeof(float));

  zero_kernel<<<1, 256, 0, stream>>>(bcnt, NB + 1);
  int gcsr = nTiles;  // 269 blocks: co-resident on 256 CUs (<=6KB LDS)
  fused_csr_kernel<<<gcsr, 256, 0, stream>>>(ei, E, Etot, NB, nTiles,
                                             bcnt, slab, N, row_start, esrc,
                                             syncc);

  int nRowTiles = (N + 63) / 64;
  int gmg = min(nRowTiles, 512);  // persistent gemm blocks
  int ga = (N + 7) / 8;           // aggregate: 8 nodes per block
  // Layer 1: GATConv(64 -> 16, heads=4, concat) + bias + ELU (fp16 out)
  mfma_gemm_kernel<4, float><<<gmg, 256, 0, stream>>>(emb, W1, as1, ad1, N, hbuf, AS, AD, nRowTiles);
  aggregate_kernel<4, false, __half><<<ga, 256, 0, stream>>>(row_start, esrc, hbuf, AS, AD, b1, N, xbuf);
  // Layer 2: GATConv(64 -> 64, heads=1) + bias + L2 normalize (fp32 out)
  mfma_gemm_kernel<1, __half><<<gmg, 256, 0, stream>>>(xbuf, W2, as2, ad2, N, hbuf, AS, AD, nRowTiles);
  aggregate_kernel<1, true, float><<<ga, 256, 0, stream>>>(row_start, esrc, hbuf, AS, AD, b2, N, out);
}

// Round 15
// 130.063 us; speedup vs baseline: 1.4647x; 1.4647x over previous
//
#include <hip/hip_runtime.h>
#include <hip/hip_fp16.h>
#include <math.h>

// GAT 2-layer forward on MI355X.
// CSR build: direct slab scatter (one pass over ei) + per-bucket counting
//            sort with inline prefix. (Fused-barrier variant REVERTED: spin
//            contention on the sync line cost 90us — R14 post-mortem.)
// Per layer:
//   mfma_gemm: grid-stride persistent blocks (1024); W^T staged once/block;
//              h = x@W via mfma_f32_16x16x32_f16, fused alpha epilogue.
//   aggregate: wave = 2 dst nodes; 8 c-lanes own 8 channels (f16x8 16B
//              gathers) x 4 edge-offset lanes; 16 edges/node in flight;
//              weight computed in-kernel (no-max softmax).

constexpr int FDIM = 64;
constexpr int BSHIFT = 9;                 // 512 nodes per bucket
constexpr int BMASK = (1 << BSHIFT) - 1;  // 511
constexpr int EDGE_TILE = 4096;           // edges per scatter block
constexpr int SLAB_CAP = 8192;            // per-bucket slab capacity (mean 5.6k)

using f16 = _Float16;
typedef f16 f16x8 __attribute__((ext_vector_type(8)));
typedef f16 f16x4 __attribute__((ext_vector_type(4)));
typedef float f32x4 __attribute__((ext_vector_type(4)));

// ---------------- small utility ----------------

__global__ void zero_kernel(int* __restrict__ p, int n) {
  int i = blockIdx.x * blockDim.x + threadIdx.x;
  if (i < n) p[i] = 0;
}

// ---------------- CSR build ----------------

__global__ __launch_bounds__(256) void tile_scatter_direct_kernel(
    const int* __restrict__ ei, int E, int Etot, int NB,
    int* __restrict__ bcnt, unsigned* __restrict__ slab) {
  __shared__ int hist[512];
  __shared__ int cur[512];
  int t = threadIdx.x;
  for (int b = t; b < NB; b += 256) hist[b] = 0;
  __syncthreads();
  int i0 = blockIdx.x * EDGE_TILE;
  int iend = min(i0 + EDGE_TILE, Etot);
  for (int i = i0 + t; i < iend; i += 256) {
    int dst = (i < E) ? ei[E + i] : (i - E);  // self-loops appended
    atomicAdd(&hist[dst >> BSHIFT], 1);
  }
  __syncthreads();
  for (int b = t; b < NB; b += 256)
    cur[b] = hist[b] ? atomicAdd(&bcnt[b], hist[b]) : 0;
  __syncthreads();
  for (int i = i0 + t; i < iend; i += 256) {
    int src, dst;
    if (i < E) { src = ei[i]; dst = ei[E + i]; }
    else       { src = i - E; dst = i - E; }
    int b = dst >> BSHIFT;
    int pos = atomicAdd(&cur[b], 1);
    if (pos < SLAB_CAP)
      slab[(size_t)b * SLAB_CAP + pos] =
          ((unsigned)src << BSHIFT) | (unsigned)(dst & BMASK);
  }
}

// One workgroup per bucket: inline prefix over bcnt, LDS hist over 512 node
// slots, block scan, row_start slice, bucket-local esrc scatter.
__global__ __launch_bounds__(256) void bucket_csr_kernel(
    const unsigned* __restrict__ slab, const int* __restrict__ bcnt,
    int N, int NB, int Etot,
    int* __restrict__ row_start, int* __restrict__ esrc) {
  __shared__ int hist[512];
  __shared__ int excl[512];
  __shared__ int cur[512];
  __shared__ int sbase;
  int b = blockIdx.x;
  int t = threadIdx.x;

  if (t < 64) {
    int ssum = 0;
    for (int i = t; i < b; i += 64) ssum += bcnt[i];
#pragma unroll
    for (int off = 32; off > 0; off >>= 1) ssum += __shfl_xor(ssum, off, 64);
    if (t == 0) sbase = ssum;
  }
  hist[t] = 0;
  hist[256 + t] = 0;
  __syncthreads();
  int base = sbase;
  int cnt = min(bcnt[b], SLAB_CAP);
  const unsigned* sp = slab + (size_t)b * SLAB_CAP;
  for (int i = t; i < cnt; i += 256)
    atomicAdd(&hist[sp[i] & (unsigned)BMASK], 1);
  __syncthreads();
  int h0 = hist[2 * t], h1 = hist[2 * t + 1];
  int s = h0 + h1;
  int lane = t & 63, w = t >> 6;
  int x = s;
#pragma unroll
  for (int off = 1; off < 64; off <<= 1) {
    int u = __shfl_up(x, off, 64);
    if (lane >= off) x += u;
  }
  __shared__ int wsum[4];
  if (lane == 63) wsum[w] = x;
  __syncthreads();
  int add = 0;
#pragma unroll
  for (int k = 0; k < 4; ++k) add += (k < w) ? wsum[k] : 0;
  int e0 = x + add - s;
  excl[2 * t] = e0;
  excl[2 * t + 1] = e0 + h0;
  cur[2 * t] = e0;
  cur[2 * t + 1] = e0 + h0;
  __syncthreads();
  int node0 = b << BSHIFT;
#pragma unroll
  for (int k = 0; k < 2; ++k) {
    int slot = k * 256 + t;
    int node = node0 + slot;
    if (node < N) row_start[node] = base + excl[slot];
  }
  if (b == NB - 1 && t == 0) row_start[N] = Etot;
  for (int i = t; i < cnt; i += 256) {
    unsigned p = sp[i];
    int pos = base + atomicAdd(&cur[p & (unsigned)BMASK], 1);
    esrc[pos] = (int)(p >> BSHIFT);
  }
}

// ---------------- MFMA GEMM (x @ W) + attention logits ----------------
// Grid-stride persistent blocks; W^T staged into LDS ONCE per block.

template <int HEADS, typename IN>
__global__ __launch_bounds__(256) void mfma_gemm_kernel(
    const IN* __restrict__ X, const float* __restrict__ W,
    const float* __restrict__ a_s, const float* __restrict__ a_d, int N,
    __half* __restrict__ H, float* __restrict__ AS, float* __restrict__ AD,
    int nRowTiles) {
  __shared__ f16 Xs[64 * 72];
  __shared__ f16 Wt[64 * 72];
  int t = threadIdx.x;

#pragma unroll
  for (int i = 0; i < 16; ++i) {
    int idx = i * 256 + t;
    int k = idx >> 6, c = idx & 63;
    Wt[c * 72 + k] = (f16)W[idx];
  }

  int lane = t & 63, wid = t >> 6;
  int m0 = wid * 16;
  int li = lane & 15, lk = lane >> 4;
  int ko = lk * 8;
  float asc[4], adc[4];
#pragma unroll
  for (int q = 0; q < 4; ++q) {
    asc[q] = a_s[q * 16 + li];
    adc[q] = a_d[q * 16 + li];
  }

  for (int tile = blockIdx.x; tile < nRowTiles; tile += gridDim.x) {
    int row0 = tile * 64;
    __syncthreads();  // prior iteration finished reading Xs (also fences Wt)
    if constexpr (sizeof(IN) == 4) {
#pragma unroll
      for (int i = 0; i < 4; ++i) {
        int idx = (i * 256 + t) * 4;
        int r = idx >> 6, k = idx & 63;
        int rg = min(row0 + r, N - 1);
        float4 f = *reinterpret_cast<const float4*>(
            reinterpret_cast<const float*>(X) + (size_t)rg * 64 + k);
        f16x4 v = {(f16)f.x, (f16)f.y, (f16)f.z, (f16)f.w};
        *reinterpret_cast<f16x4*>(&Xs[r * 72 + k]) = v;
      }
    } else {
#pragma unroll
      for (int i = 0; i < 2; ++i) {
        int idx = (i * 256 + t) * 8;
        int r = idx >> 6, k = idx & 63;
        int rg = min(row0 + r, N - 1);
        f16x8 v = *reinterpret_cast<const f16x8*>(
            reinterpret_cast<const f16*>(X) + (size_t)rg * 64 + k);
        *reinterpret_cast<f16x8*>(&Xs[r * 72 + k]) = v;
      }
    }
    __syncthreads();

    f16x8 a_lo = *reinterpret_cast<const f16x8*>(&Xs[(m0 + li) * 72 + ko]);
    f16x8 a_hi = *reinterpret_cast<const f16x8*>(&Xs[(m0 + li) * 72 + 32 + ko]);

    f32x4 acc[4];
#pragma unroll
    for (int q = 0; q < 4; ++q) acc[q] = (f32x4){0.f, 0.f, 0.f, 0.f};
#pragma unroll
    for (int q = 0; q < 4; ++q) {
      int c0 = q * 16 + li;
      f16x8 b_lo = *reinterpret_cast<const f16x8*>(&Wt[c0 * 72 + ko]);
      f16x8 b_hi = *reinterpret_cast<const f16x8*>(&Wt[c0 * 72 + 32 + ko]);
      acc[q] = __builtin_amdgcn_mfma_f32_16x16x32_f16(a_lo, b_lo, acc[q], 0, 0, 0);
      acc[q] = __builtin_amdgcn_mfma_f32_16x16x32_f16(a_hi, b_hi, acc[q], 0, 0, 0);
    }

    int rbase = row0 + m0 + lk * 4;
#pragma unroll
    for (int r = 0; r < 4; ++r) {
      int grow = rbase + r;
      if (grow < N) {
#pragma unroll
        for (int q = 0; q < 4; ++q)
          H[(size_t)grow * 64 + q * 16 + li] = __float2half((float)acc[q][r]);
      }
    }

    if constexpr (HEADS == 4) {
      float ps[4][4], pd[4][4];
#pragma unroll
      for (int q = 0; q < 4; ++q)
#pragma unroll
        for (int r = 0; r < 4; ++r) {
          ps[q][r] = (float)acc[q][r] * asc[q];
          pd[q][r] = (float)acc[q][r] * adc[q];
        }
#pragma unroll
      for (int off = 1; off < 16; off <<= 1)
#pragma unroll
        for (int q = 0; q < 4; ++q)
#pragma unroll
          for (int r = 0; r < 4; ++r) {
            ps[q][r] += __shfl_xor(ps[q][r], off, 64);
            pd[q][r] += __shfl_xor(pd[q][r], off, 64);
          }
      if (li == 0) {
#pragma unroll
        for (int r = 0; r < 4; ++r) {
          int grow = rbase + r;
          if (grow < N) {
#pragma unroll
            for (int q = 0; q < 4; ++q) {
              AS[(size_t)grow * 4 + q] = ps[q][r];
              AD[(size_t)grow * 4 + q] = pd[q][r];
            }
          }
        }
      }
    } else {
      float ps[4], pd[4];
#pragma unroll
      for (int r = 0; r < 4; ++r) {
        ps[r] = 0.f; pd[r] = 0.f;
#pragma unroll
        for (int q = 0; q < 4; ++q) {
          ps[r] = fmaf((float)acc[q][r], asc[q], ps[r]);
          pd[r] = fmaf((float)acc[q][r], adc[q], pd[r]);
        }
      }
#pragma unroll
      for (int off = 1; off < 16; off <<= 1)
#pragma unroll
        for (int r = 0; r < 4; ++r) {
          ps[r] += __shfl_xor(ps[r], off, 64);
          pd[r] += __shfl_xor(pd[r], off, 64);
        }
      if (li == 0) {
#pragma unroll
        for (int r = 0; r < 4; ++r) {
          int grow = rbase + r;
          if (grow < N) { AS[grow] = ps[r]; AD[grow] = pd[r]; }
        }
      }
    }
  }
}

// ---------------- aggregation (f16x8 channels, 16 edges in flight) --------

template <int HEADS, bool FINAL, typename OUTT>
__global__ __launch_bounds__(256) void aggregate_kernel(
    const int* __restrict__ row_start, const int* __restrict__ esrc,
    const __half* __restrict__ H, const float* __restrict__ AS,
    const float* __restrict__ AD, const float* __restrict__ bias, int N,
    OUTT* __restrict__ OUT) {
  int t = threadIdx.x;
  int wid = t >> 6;
  int half = (t >> 5) & 1;
  int ll = t & 31;
  int c = ll & 7;            // channel octet: channels 8c..8c+7
  int eo = ll >> 3;          // edge offset lane 0..3
  int n = blockIdx.x * 8 + wid * 2 + half;

  int head = (HEADS == 4) ? (c >> 1) : 0;

  int rs = 0, re = 0;
  float ad = 0.f;
  if (n < N) {
    rs = row_start[n];
    re = row_start[n + 1];
    ad = AD[(size_t)n * HEADS + head];
  }
  int deg = re - rs;
  int degO = __shfl_xor(deg, 32, 64);
  int degmax = max(deg, degO);

  const f16* Hp = reinterpret_cast<const f16*>(H);

  float d = 0.f;
  float a[8] = {0.f, 0.f, 0.f, 0.f, 0.f, 0.f, 0.f, 0.f};

  for (int i = 0; i < degmax; i += 16) {
    int sv[4];
    float ev[4];
    f16x8 hv[4];
#pragma unroll
    for (int k = 0; k < 4; ++k) {
      int o = i + 4 * k + eo;
      int oc = max(min(o, deg - 1), 0);  // deg >= 1 always (self-loops)
      sv[k] = esrc[rs + oc];
    }
#pragma unroll
    for (int k = 0; k < 4; ++k) {
      ev[k] = AS[(unsigned)sv[k] * HEADS + (unsigned)head];
      hv[k] = *reinterpret_cast<const f16x8*>(&Hp[(size_t)sv[k] * 64 + c * 8]);
    }
#pragma unroll
    for (int k = 0; k < 4; ++k) {
      int o = i + 4 * k + eo;
      float e = ev[k] + ad;
      e = fmaxf(e, 0.2f * e);            // LeakyReLU(0.2)
      float w = (o < deg) ? __expf(e) : 0.f;
      d += w;
#pragma unroll
      for (int j = 0; j < 8; ++j) a[j] = fmaf(w, (float)hv[k][j], a[j]);
    }
  }

  // merge the 4 edge-offset lanes (xor 8,16 stay within the node's 32 lanes)
  d += __shfl_xor(d, 8, 64);
  d += __shfl_xor(d, 16, 64);
#pragma unroll
  for (int j = 0; j < 8; ++j) {
    a[j] += __shfl_xor(a[j], 8, 64);
    a[j] += __shfl_xor(a[j], 16, 64);
  }

  if (n >= N) return;

  float inv = 1.f / (d + 1e-16f);
  float4 b0 = reinterpret_cast<const float4*>(bias)[c * 2];
  float4 b1 = reinterpret_cast<const float4*>(bias)[c * 2 + 1];
  float v[8];
  v[0] = a[0] * inv + b0.x;
  v[1] = a[1] * inv + b0.y;
  v[2] = a[2] * inv + b0.z;
  v[3] = a[3] * inv + b0.w;
  v[4] = a[4] * inv + b1.x;
  v[5] = a[5] * inv + b1.y;
  v[6] = a[6] * inv + b1.z;
  v[7] = a[7] * inv + b1.w;

  if constexpr (FINAL) {
    float ss = 0.f;
#pragma unroll
    for (int j = 0; j < 8; ++j) ss += v[j] * v[j];
    ss += __shfl_xor(ss, 1, 64);
    ss += __shfl_xor(ss, 2, 64);
    ss += __shfl_xor(ss, 4, 64);
    float rn = 1.f / fmaxf(sqrtf(ss), 1e-12f);
    if (eo == 0) {
      float4* O4 = reinterpret_cast<float4*>(OUT);
      O4[(size_t)n * 16 + c * 2] =
          make_float4(v[0] * rn, v[1] * rn, v[2] * rn, v[3] * rn);
      O4[(size_t)n * 16 + c * 2 + 1] =
          make_float4(v[4] * rn, v[5] * rn, v[6] * rn, v[7] * rn);
    }
  } else {
#pragma unroll
    for (int j = 0; j < 8; ++j) v[j] = v[j] > 0.f ? v[j] : expm1f(v[j]);
    if (eo == 0) {
      f16x8 o = {(f16)v[0], (f16)v[1], (f16)v[2], (f16)v[3],
                 (f16)v[4], (f16)v[5], (f16)v[6], (f16)v[7]};
      reinterpret_cast<f16x8*>(OUT)[(size_t)n * 8 + c] = o;
    }
  }
}

// ---------------- launch ----------------

extern "C" void kernel_launch(void* const* d_in, const int* in_sizes, int n_in,
                              void* d_out, int out_size, void* d_ws,
                              size_t ws_size, hipStream_t stream) {
  const int* ei = (const int*)d_in[0];          // [2, E]
  const float* emb = (const float*)d_in[1];     // [N, 64]
  const float* W1 = (const float*)d_in[2];
  const float* as1 = (const float*)d_in[3];
  const float* ad1 = (const float*)d_in[4];
  const float* b1 = (const float*)d_in[5];
  const float* W2 = (const float*)d_in[6];
  const float* as2 = (const float*)d_in[7];
  const float* ad2 = (const float*)d_in[8];
  const float* b2 = (const float*)d_in[9];
  float* out = (float*)d_out;

  int E = in_sizes[0] / 2;
  int N = in_sizes[1] / FDIM;
  int Etot = E + N;
  int NB = (N + BMASK) >> BSHIFT;           // buckets of 512 nodes
  int nTiles = (Etot + EDGE_TILE - 1) / EDGE_TILE;

  char* ws = (char*)d_ws;
  size_t off = 0;
  auto alloc = [&](size_t bytes) -> void* {
    void* p = ws + off;
    off += (bytes + 255) & ~(size_t)255;
    return p;
  };
  int* bcnt = (int*)alloc((size_t)NB * sizeof(int));
  unsigned* slab = (unsigned*)alloc((size_t)NB * SLAB_CAP * sizeof(unsigned));
  int* row_start = (int*)alloc((size_t)(N + 1) * sizeof(int));
  int* esrc = (int*)alloc((size_t)Etot * sizeof(int));
  __half* hbuf = (__half*)alloc((size_t)N * FDIM * sizeof(__half));
  __half* xbuf = (__half*)alloc((size_t)N * FDIM * sizeof(__half));
  float* AS = (float*)alloc((size_t)N * 4 * sizeof(float));
  float* AD = (float*)alloc((size_t)N * 4 * sizeof(float));

  zero_kernel<<<(NB + 255) / 256, 256, 0, stream>>>(bcnt, NB);
  tile_scatter_direct_kernel<<<nTiles, 256, 0, stream>>>(ei, E, Etot, NB,
                                                         bcnt, slab);
  bucket_csr_kernel<<<NB, 256, 0, stream>>>(slab, bcnt, N, NB, Etot,
                                            row_start, esrc);

  int nRowTiles = (N + 63) / 64;
  int gmg = min(nRowTiles, 1024);  // persistent gemm blocks (4/CU)
  int ga = (N + 7) / 8;            // aggregate: 8 nodes per block
  // Layer 1: GATConv(64 -> 16, heads=4, concat) + bias + ELU (fp16 out)
  mfma_gemm_kernel<4, float><<<gmg, 256, 0, stream>>>(emb, W1, as1, ad1, N, hbuf, AS, AD, nRowTiles);
  aggregate_kernel<4, false, __half><<<ga, 256, 0, stream>>>(row_start, esrc, hbuf, AS, AD, b1, N, xbuf);
  // Layer 2: GATConv(64 -> 64, heads=1) + bias + L2 normalize (fp32 out)
  mfma_gemm_kernel<1, __half><<<gmg, 256, 0, stream>>>(xbuf, W2, as2, ad2, N, hbuf, AS, AD, nRowTiles);
  aggregate_kernel<1, true, float><<<ga, 256, 0, stream>>>(row_start, esrc, hbuf, AS, AD, b2, N, out);
}